// Round 1
// baseline (48828.494 us; speedup 1.0000x reference)
//
#include <hip/hip_runtime.h>

// ---------------------------------------------------------------------------
// GCN autoencoder, fp32 baseline.
//   h  = spmm(x@w0)+b0 ; h = bn(relu(h))
//   xo = spmm(h@w1)+b1
//   r  = spmm(relu(xo)@dw0)+db0 ; r = bn(relu(r))
//   xr = spmm(r@dw1)+db1
// d_out = [xo (N*128) | xr (N*512)].  xr region doubles as scratch (recA/recB)
// until the final spmm. d_ws: [wsbig N*512 | stats 1024 floats].
// ---------------------------------------------------------------------------

// ---------- GEMM: C[N,K] = act(A)[N,M] @ W[M,K], M%16==0, K%64==0 ----------
template <bool RELU_A>
__global__ __launch_bounds__(256) void gemm_tile(const float* __restrict__ A,
                                                 const float* __restrict__ W,
                                                 float* __restrict__ C,
                                                 int Nrows, int M, int K) {
    __shared__ float As[16][68];  // [k][m], row stride 68 floats (16B aligned)
    __shared__ float Ws[16][68];  // [k][n]
    const int tid = threadIdx.x;
    const int tx = tid & 15;   // output col group (4 cols)
    const int ty = tid >> 4;   // output row group (4 rows)
    const int row0 = blockIdx.y * 64;
    const int col0 = blockIdx.x * 64;

    float acc[4][4];
#pragma unroll
    for (int i = 0; i < 4; ++i)
#pragma unroll
        for (int j = 0; j < 4; ++j) acc[i][j] = 0.f;

    const int ar = tid >> 2;         // 0..63  (A tile row)
    const int ak = (tid & 3) << 2;   // 0,4,8,12 (A tile k)
    const int wr = tid >> 4;         // 0..15  (W tile k)
    const int wc = (tid & 15) << 2;  // 0..60  (W tile col)

    for (int k0 = 0; k0 < M; k0 += 16) {
        float4 av = make_float4(0.f, 0.f, 0.f, 0.f);
        const int grow = row0 + ar;
        if (grow < Nrows) av = *(const float4*)(A + (size_t)grow * M + (k0 + ak));
        if (RELU_A) {
            av.x = fmaxf(av.x, 0.f); av.y = fmaxf(av.y, 0.f);
            av.z = fmaxf(av.z, 0.f); av.w = fmaxf(av.w, 0.f);
        }
        As[ak + 0][ar] = av.x; As[ak + 1][ar] = av.y;
        As[ak + 2][ar] = av.z; As[ak + 3][ar] = av.w;

        float4 wv = *(const float4*)(W + (size_t)(k0 + wr) * K + (col0 + wc));
        *(float4*)&Ws[wr][wc] = wv;
        __syncthreads();

#pragma unroll
        for (int kk = 0; kk < 16; ++kk) {
            const float4 a = *(const float4*)&As[kk][ty << 2];
            const float4 b = *(const float4*)&Ws[kk][tx << 2];
            acc[0][0] += a.x * b.x; acc[0][1] += a.x * b.y; acc[0][2] += a.x * b.z; acc[0][3] += a.x * b.w;
            acc[1][0] += a.y * b.x; acc[1][1] += a.y * b.y; acc[1][2] += a.y * b.z; acc[1][3] += a.y * b.w;
            acc[2][0] += a.z * b.x; acc[2][1] += a.z * b.y; acc[2][2] += a.z * b.z; acc[2][3] += a.z * b.w;
            acc[3][0] += a.w * b.x; acc[3][1] += a.w * b.y; acc[3][2] += a.w * b.z; acc[3][3] += a.w * b.w;
        }
        __syncthreads();
    }

#pragma unroll
    for (int i = 0; i < 4; ++i) {
        const int grow = row0 + (ty << 2) + i;
        if (grow < Nrows) {
            float4 o = make_float4(acc[i][0], acc[i][1], acc[i][2], acc[i][3]);
            *(float4*)(C + (size_t)grow * K + col0 + (tx << 2)) = o;
        }
    }
}

// ---------- out[n, :] = bias[:]  (float4 granular; F power of two) ----------
__global__ void fill_bias(float* __restrict__ out, const float* __restrict__ bias,
                          size_t n4, unsigned maskF4) {
    const size_t i = (size_t)blockIdx.x * blockDim.x + threadIdx.x;
    if (i >= n4) return;
    const int cb = (int)(i & maskF4) << 2;
    ((float4*)out)[i] = *(const float4*)(bias + cb);
}

// ---------- SpMM scatter: out[rows[e], :] += vals[e] * H[cols[e], :] -------
__global__ void spmm_edges(const int* __restrict__ rows, const int* __restrict__ cols,
                           const float* __restrict__ vals, const float* __restrict__ H,
                           float* __restrict__ out, int E, int F, int log2chunks) {
    const size_t idx = (size_t)blockIdx.x * blockDim.x + threadIdx.x;
    const int e = (int)(idx >> log2chunks);
    if (e >= E) return;
    const int c = (int)(idx & ((1u << log2chunks) - 1u));
    const int dst = rows[e];
    const int src = cols[e];
    const float v = vals[e];
    const float4 h = *(const float4*)(H + (size_t)src * F + (c << 2));
    float* o = out + (size_t)dst * F + (c << 2);
    atomicAdd(o + 0, v * h.x);
    atomicAdd(o + 1, v * h.y);
    atomicAdd(o + 2, v * h.z);
    atomicAdd(o + 3, v * h.w);
}

// ---------- BN helpers (C == 256, blockDim == 256) -------------------------
__global__ void zero_stats(float* __restrict__ p) { p[threadIdx.x] = 0.f; }

// stats layout: sum[0..255] sq[256..511] mean[512..767] inv[768..1023]
__global__ void bn_stats(const float* __restrict__ H, float* __restrict__ stats,
                         int Nrows) {
    const int c = threadIdx.x;  // 256 threads
    float s = 0.f, q = 0.f;
    for (int n = blockIdx.x; n < Nrows; n += gridDim.x) {
        float h = H[(size_t)n * 256 + c];
        h = fmaxf(h, 0.f);
        s += h;
        q += h * h;
    }
    atomicAdd(&stats[c], s);
    atomicAdd(&stats[256 + c], q);
}

__global__ void bn_finalize(float* __restrict__ stats, float invN) {
    const int c = threadIdx.x;  // 256 threads
    const float m = stats[c] * invN;
    const float q = stats[256 + c] * invN;
    const float var = q - m * m;
    stats[512 + c] = m;
    stats[768 + c] = rsqrtf(var + 1e-5f);
}

// out[n,c] = (relu(H[n,c]) - mean[c]) * inv[c], C=256, float4 granular
__global__ void bn_apply(const float* __restrict__ H, const float* __restrict__ stats,
                         float* __restrict__ out, size_t n4) {
    const size_t i = (size_t)blockIdx.x * blockDim.x + threadIdx.x;
    if (i >= n4) return;
    const int cb = (int)(i & 63u) << 2;
    const float4 h = ((const float4*)H)[i];
    const float4 m = *(const float4*)(stats + 512 + cb);
    const float4 s = *(const float4*)(stats + 768 + cb);
    float4 o;
    o.x = (fmaxf(h.x, 0.f) - m.x) * s.x;
    o.y = (fmaxf(h.y, 0.f) - m.y) * s.y;
    o.z = (fmaxf(h.z, 0.f) - m.z) * s.z;
    o.w = (fmaxf(h.w, 0.f) - m.w) * s.w;
    ((float4*)out)[i] = o;
}

// ---------------------------------------------------------------------------
extern "C" void kernel_launch(void* const* d_in, const int* in_sizes, int n_in,
                              void* d_out, int out_size, void* d_ws, size_t ws_size,
                              hipStream_t stream) {
    const float* x    = (const float*)d_in[0];
    const int*   rows = (const int*)d_in[1];
    const int*   cols = (const int*)d_in[2];
    const float* vals = (const float*)d_in[3];
    const float* w0   = (const float*)d_in[4];
    const float* b0   = (const float*)d_in[5];
    const float* w1   = (const float*)d_in[6];
    const float* b1   = (const float*)d_in[7];
    const float* dw0  = (const float*)d_in[8];
    const float* db0  = (const float*)d_in[9];
    const float* dw1  = (const float*)d_in[10];
    const float* db1  = (const float*)d_in[11];

    const int N = in_sizes[0] / 512;
    const int E = in_sizes[1];

    float* xout  = (float*)d_out;              // N*128
    float* rec   = xout + (size_t)N * 128;     // N*512 (final x_rec; scratch until then)
    float* recA  = rec;                        // N*256
    float* recB  = rec + (size_t)N * 256;      // N*256
    float* wsbig = (float*)d_ws;               // N*512
    float* stats = wsbig + (size_t)N * 512;    // 1024 floats

    const dim3 blk(256);
    const int gy = (N + 63) / 64;

    // 1. t0 = x @ w0 -> recA
    gemm_tile<false><<<dim3(256 / 64, gy), blk, 0, stream>>>(x, w0, recA, N, 512, 256);

    // 2. t1 = spmm(t0) + b0 -> recB
    {
        const size_t n4 = (size_t)N * 256 / 4;
        fill_bias<<<dim3((unsigned)((n4 + 255) / 256)), blk, 0, stream>>>(recB, b0, n4, 63u);
        const size_t tot = (size_t)E * 64;
        spmm_edges<<<dim3((unsigned)((tot + 255) / 256)), blk, 0, stream>>>(
            rows, cols, vals, recA, recB, E, 256, 6);
    }

    // 3. t2 = bn(relu(t1)) -> recA
    zero_stats<<<dim3(1), dim3(512), 0, stream>>>(stats);
    bn_stats<<<dim3(512), blk, 0, stream>>>(recB, stats, N);
    bn_finalize<<<dim3(1), blk, 0, stream>>>(stats, 1.0f / (float)N);
    {
        const size_t n4 = (size_t)N * 256 / 4;
        bn_apply<<<dim3((unsigned)((n4 + 255) / 256)), blk, 0, stream>>>(recB, stats, recA, n4);
    }

    // 4. t3 = t2 @ w1 -> wsbig (N*128)
    gemm_tile<false><<<dim3(128 / 64, gy), blk, 0, stream>>>(recA, w1, wsbig, N, 256, 128);

    // 5. x_out = spmm(t3) + b1 -> xout
    {
        const size_t n4 = (size_t)N * 128 / 4;
        fill_bias<<<dim3((unsigned)((n4 + 255) / 256)), blk, 0, stream>>>(xout, b1, n4, 31u);
        const size_t tot = (size_t)E * 32;
        spmm_edges<<<dim3((unsigned)((tot + 255) / 256)), blk, 0, stream>>>(
            rows, cols, vals, wsbig, xout, E, 128, 5);
    }

    // 6. r1 = relu(x_out) @ dw0 -> recB
    gemm_tile<true><<<dim3(256 / 64, gy), blk, 0, stream>>>(xout, dw0, recB, N, 128, 256);

    // 7. r2 = spmm(r1) + db0 -> recA
    {
        const size_t n4 = (size_t)N * 256 / 4;
        fill_bias<<<dim3((unsigned)((n4 + 255) / 256)), blk, 0, stream>>>(recA, db0, n4, 63u);
        const size_t tot = (size_t)E * 64;
        spmm_edges<<<dim3((unsigned)((tot + 255) / 256)), blk, 0, stream>>>(
            rows, cols, vals, recB, recA, E, 256, 6);
    }

    // 8. r3 = bn(relu(r2)) -> recB
    zero_stats<<<dim3(1), dim3(512), 0, stream>>>(stats);
    bn_stats<<<dim3(512), blk, 0, stream>>>(recA, stats, N);
    bn_finalize<<<dim3(1), blk, 0, stream>>>(stats, 1.0f / (float)N);
    {
        const size_t n4 = (size_t)N * 256 / 4;
        bn_apply<<<dim3((unsigned)((n4 + 255) / 256)), blk, 0, stream>>>(recA, stats, recB, n4);
    }

    // 9. r4 = r3 @ dw1 -> wsbig (N*512)
    gemm_tile<false><<<dim3(512 / 64, gy), blk, 0, stream>>>(recB, dw1, wsbig, N, 256, 512);

    // 10. x_rec = spmm(r4) + db1 -> rec  (overwrites recA/recB scratch)
    {
        const size_t n4 = (size_t)N * 512 / 4;
        fill_bias<<<dim3((unsigned)((n4 + 255) / 256)), blk, 0, stream>>>(rec, db1, n4, 127u);
        const size_t tot = (size_t)E * 128;
        spmm_edges<<<dim3((unsigned)((tot + 255) / 256)), blk, 0, stream>>>(
            rows, cols, vals, wsbig, rec, E, 512, 7);
    }
}

// Round 2
// 3730.889 us; speedup vs baseline: 13.0876x; 13.0876x over previous
//
#include <hip/hip_runtime.h>

// ---------------------------------------------------------------------------
// GCN autoencoder, fp32, CSR gather-spmm.
//   h  = spmm(x@w0)+b0 ; h = bn(relu(h))
//   xo = spmm(h@w1)+b1
//   r  = spmm(relu(xo)@dw0)+db0 ; r = bn(relu(r))
//   xr = spmm(r@dw1)+db1
// d_out = [xo (N*128) | xr (N*512)].  xr region doubles as scratch (recA/recB)
// until the final spmm.
// ws (CSR path): [wsbig N*512 f32][stats 1024 f32][row_start N+1][cursor N]
//                [blockSums 256][sc E int][sv E f32]
// Falls back to the R0 atomic-scatter path if ws_size is too small (ws_size is
// constant across calls, so both paths are graph-capture-safe).
// ---------------------------------------------------------------------------

// ---------- GEMM: C[N,K] = act(A)[N,M] @ W[M,K], M%16==0, K%64==0 ----------
template <bool RELU_A>
__global__ __launch_bounds__(256) void gemm_tile(const float* __restrict__ A,
                                                 const float* __restrict__ W,
                                                 float* __restrict__ C,
                                                 int Nrows, int M, int K) {
    __shared__ float As[16][68];  // [k][m]
    __shared__ float Ws[16][68];  // [k][n]
    const int tid = threadIdx.x;
    const int tx = tid & 15;
    const int ty = tid >> 4;
    const int row0 = blockIdx.y * 64;
    const int col0 = blockIdx.x * 64;

    float acc[4][4];
#pragma unroll
    for (int i = 0; i < 4; ++i)
#pragma unroll
        for (int j = 0; j < 4; ++j) acc[i][j] = 0.f;

    const int ar = tid >> 2;
    const int ak = (tid & 3) << 2;
    const int wr = tid >> 4;
    const int wc = (tid & 15) << 2;

    for (int k0 = 0; k0 < M; k0 += 16) {
        float4 av = make_float4(0.f, 0.f, 0.f, 0.f);
        const int grow = row0 + ar;
        if (grow < Nrows) av = *(const float4*)(A + (size_t)grow * M + (k0 + ak));
        if (RELU_A) {
            av.x = fmaxf(av.x, 0.f); av.y = fmaxf(av.y, 0.f);
            av.z = fmaxf(av.z, 0.f); av.w = fmaxf(av.w, 0.f);
        }
        As[ak + 0][ar] = av.x; As[ak + 1][ar] = av.y;
        As[ak + 2][ar] = av.z; As[ak + 3][ar] = av.w;

        float4 wv = *(const float4*)(W + (size_t)(k0 + wr) * K + (col0 + wc));
        *(float4*)&Ws[wr][wc] = wv;
        __syncthreads();

#pragma unroll
        for (int kk = 0; kk < 16; ++kk) {
            const float4 a = *(const float4*)&As[kk][ty << 2];
            const float4 b = *(const float4*)&Ws[kk][tx << 2];
            acc[0][0] += a.x * b.x; acc[0][1] += a.x * b.y; acc[0][2] += a.x * b.z; acc[0][3] += a.x * b.w;
            acc[1][0] += a.y * b.x; acc[1][1] += a.y * b.y; acc[1][2] += a.y * b.z; acc[1][3] += a.y * b.w;
            acc[2][0] += a.z * b.x; acc[2][1] += a.z * b.y; acc[2][2] += a.z * b.z; acc[2][3] += a.z * b.w;
            acc[3][0] += a.w * b.x; acc[3][1] += a.w * b.y; acc[3][2] += a.w * b.z; acc[3][3] += a.w * b.w;
        }
        __syncthreads();
    }

#pragma unroll
    for (int i = 0; i < 4; ++i) {
        const int grow = row0 + (ty << 2) + i;
        if (grow < Nrows) {
            float4 o = make_float4(acc[i][0], acc[i][1], acc[i][2], acc[i][3]);
            *(float4*)(C + (size_t)grow * K + col0 + (tx << 2)) = o;
        }
    }
}

// ====================== CSR build ==========================================
__global__ void zero_ints(int* __restrict__ p, int n) {
    const int i = blockIdx.x * blockDim.x + threadIdx.x;
    if (i < n) p[i] = 0;
}

__global__ void hist_rows(const int* __restrict__ rows, int* __restrict__ cnt, int E) {
    const int e = blockIdx.x * blockDim.x + threadIdx.x;
    if (e < E) atomicAdd(&cnt[rows[e]], 1);
}

// per-block (1024 items) reduction of counts -> blockSums
__global__ __launch_bounds__(256) void scan_reduce(const int* __restrict__ cnt,
                                                   int* __restrict__ blockSums, int Nrows) {
    __shared__ int sh[256];
    const int t = threadIdx.x;
    const int idx0 = blockIdx.x * 1024 + t * 4;
    int s = 0;
#pragma unroll
    for (int k = 0; k < 4; ++k) s += (idx0 + k < Nrows) ? cnt[idx0 + k] : 0;
    sh[t] = s;
    __syncthreads();
    for (int d = 128; d > 0; d >>= 1) {
        if (t < d) sh[t] += sh[t + d];
        __syncthreads();
    }
    if (t == 0) blockSums[blockIdx.x] = sh[0];
}

// single block: exclusive scan of blockSums (NB <= 256); also row_start[N]=E
__global__ __launch_bounds__(256) void scan_blocksums(int* __restrict__ blockSums, int NB,
                                                      int* __restrict__ row_start, int Nrows,
                                                      int E) {
    __shared__ int sh[256];
    const int t = threadIdx.x;
    const int v = (t < NB) ? blockSums[t] : 0;
    sh[t] = v;
    __syncthreads();
    for (int d = 1; d < 256; d <<= 1) {
        int add = (t >= d) ? sh[t - d] : 0;
        __syncthreads();
        sh[t] += add;
        __syncthreads();
    }
    if (t < NB) blockSums[t] = sh[t] - v;  // exclusive
    if (t == 0) row_start[Nrows] = E;
}

// per-block local exclusive scan + block offset -> row_start & cursor
__global__ __launch_bounds__(256) void scan_final(const int* __restrict__ cnt,
                                                  const int* __restrict__ blockSums,
                                                  int* __restrict__ row_start,
                                                  int* __restrict__ cursor, int Nrows) {
    __shared__ int sh[256];
    const int t = threadIdx.x;
    const int idx0 = blockIdx.x * 1024 + t * 4;
    int c[4];
    int mySum = 0;
#pragma unroll
    for (int k = 0; k < 4; ++k) {
        c[k] = (idx0 + k < Nrows) ? cnt[idx0 + k] : 0;
        mySum += c[k];
    }
    sh[t] = mySum;
    __syncthreads();
    for (int d = 1; d < 256; d <<= 1) {
        int add = (t >= d) ? sh[t - d] : 0;
        __syncthreads();
        sh[t] += add;
        __syncthreads();
    }
    int running = blockSums[blockIdx.x] + sh[t] - mySum;
#pragma unroll
    for (int k = 0; k < 4; ++k) {
        if (idx0 + k < Nrows) {
            row_start[idx0 + k] = running;
            cursor[idx0 + k] = running;
        }
        running += c[k];
    }
}

__global__ void scatter_edges(const int* __restrict__ rows, const int* __restrict__ cols,
                              const float* __restrict__ vals, int* __restrict__ cursor,
                              int* __restrict__ sc, float* __restrict__ sv, int E) {
    const int e = blockIdx.x * blockDim.x + threadIdx.x;
    if (e >= E) return;
    const int pos = atomicAdd(&cursor[rows[e]], 1);
    sc[pos] = cols[e];
    sv[pos] = vals[e];
}

// ---------- gather SpMM: out[r,:] = bias + sum_e sv[e]*H[sc[e],:] ----------
// one wave per row; VW = F/64 floats per lane (2, 4, or 8)
template <int VW>
__global__ __launch_bounds__(256) void spmm_csr(const int* __restrict__ row_start,
                                                const int* __restrict__ sc,
                                                const float* __restrict__ sv,
                                                const float* __restrict__ H,
                                                const float* __restrict__ bias,
                                                float* __restrict__ out, int Nrows, int F) {
    const int lane = threadIdx.x & 63;
    const int r = blockIdx.x * 4 + (threadIdx.x >> 6);
    if (r >= Nrows) return;
    const int s = row_start[r];
    const int e_end = row_start[r + 1];

    float acc[VW];
#pragma unroll
    for (int i = 0; i < VW; ++i) acc[i] = bias[lane * VW + i];

    for (int base = s; base < e_end; base += 64) {
        const int n = min(64, e_end - base);
        int cL = 0;
        float vL = 0.f;
        if (lane < n) { cL = sc[base + lane]; vL = sv[base + lane]; }
        for (int j = 0; j < n; ++j) {
            const int cj = __shfl(cL, j);
            const float vj = __shfl(vL, j);
            const float* hp = H + (size_t)cj * F + lane * VW;
            if (VW == 2) {
                const float2 h = *(const float2*)hp;
                acc[0] += vj * h.x;
                acc[1] += vj * h.y;
            } else {
#pragma unroll
                for (int q = 0; q < VW; q += 4) {
                    const float4 h = *(const float4*)(hp + q);
                    acc[q + 0] += vj * h.x;
                    acc[q + 1] += vj * h.y;
                    acc[q + 2] += vj * h.z;
                    acc[q + 3] += vj * h.w;
                }
            }
        }
    }

    float* op = out + (size_t)r * F + lane * VW;
    if (VW == 2) {
        *(float2*)op = make_float2(acc[0], acc[1]);
    } else {
#pragma unroll
        for (int q = 0; q < VW; q += 4)
            *(float4*)(op + q) = make_float4(acc[q], acc[q + 1], acc[q + 2], acc[q + 3]);
    }
}

// ====================== fallback atomic path ===============================
__global__ void fill_bias(float* __restrict__ out, const float* __restrict__ bias,
                          size_t n4, unsigned maskF4) {
    const size_t i = (size_t)blockIdx.x * blockDim.x + threadIdx.x;
    if (i >= n4) return;
    const int cb = (int)(i & maskF4) << 2;
    ((float4*)out)[i] = *(const float4*)(bias + cb);
}

__global__ void spmm_edges(const int* __restrict__ rows, const int* __restrict__ cols,
                           const float* __restrict__ vals, const float* __restrict__ H,
                           float* __restrict__ out, int E, int F, int log2chunks) {
    const size_t idx = (size_t)blockIdx.x * blockDim.x + threadIdx.x;
    const int e = (int)(idx >> log2chunks);
    if (e >= E) return;
    const int c = (int)(idx & ((1u << log2chunks) - 1u));
    const int dst = rows[e];
    const int src = cols[e];
    const float v = vals[e];
    const float4 h = *(const float4*)(H + (size_t)src * F + (c << 2));
    float* o = out + (size_t)dst * F + (c << 2);
    atomicAdd(o + 0, v * h.x);
    atomicAdd(o + 1, v * h.y);
    atomicAdd(o + 2, v * h.z);
    atomicAdd(o + 3, v * h.w);
}

// ====================== BN (C == 256) ======================================
__global__ void zero_stats(float* __restrict__ p) { p[threadIdx.x] = 0.f; }

__global__ void bn_stats(const float* __restrict__ H, float* __restrict__ stats, int Nrows) {
    const int c = threadIdx.x;
    float s = 0.f, q = 0.f;
    for (int n = blockIdx.x; n < Nrows; n += gridDim.x) {
        float h = H[(size_t)n * 256 + c];
        h = fmaxf(h, 0.f);
        s += h;
        q += h * h;
    }
    atomicAdd(&stats[c], s);
    atomicAdd(&stats[256 + c], q);
}

__global__ void bn_finalize(float* __restrict__ stats, float invN) {
    const int c = threadIdx.x;
    const float m = stats[c] * invN;
    const float q = stats[256 + c] * invN;
    const float var = q - m * m;
    stats[512 + c] = m;
    stats[768 + c] = rsqrtf(var + 1e-5f);
}

__global__ void bn_apply(const float* __restrict__ H, const float* __restrict__ stats,
                         float* __restrict__ out, size_t n4) {
    const size_t i = (size_t)blockIdx.x * blockDim.x + threadIdx.x;
    if (i >= n4) return;
    const int cb = (int)(i & 63u) << 2;
    const float4 h = ((const float4*)H)[i];
    const float4 m = *(const float4*)(stats + 512 + cb);
    const float4 s = *(const float4*)(stats + 768 + cb);
    float4 o;
    o.x = (fmaxf(h.x, 0.f) - m.x) * s.x;
    o.y = (fmaxf(h.y, 0.f) - m.y) * s.y;
    o.z = (fmaxf(h.z, 0.f) - m.z) * s.z;
    o.w = (fmaxf(h.w, 0.f) - m.w) * s.w;
    ((float4*)out)[i] = o;
}

// ---------------------------------------------------------------------------
extern "C" void kernel_launch(void* const* d_in, const int* in_sizes, int n_in,
                              void* d_out, int out_size, void* d_ws, size_t ws_size,
                              hipStream_t stream) {
    const float* x    = (const float*)d_in[0];
    const int*   rows = (const int*)d_in[1];
    const int*   cols = (const int*)d_in[2];
    const float* vals = (const float*)d_in[3];
    const float* w0   = (const float*)d_in[4];
    const float* b0   = (const float*)d_in[5];
    const float* w1   = (const float*)d_in[6];
    const float* b1   = (const float*)d_in[7];
    const float* dw0  = (const float*)d_in[8];
    const float* db0  = (const float*)d_in[9];
    const float* dw1  = (const float*)d_in[10];
    const float* db1  = (const float*)d_in[11];

    const int N = in_sizes[0] / 512;
    const int E = in_sizes[1];

    float* xout  = (float*)d_out;           // N*128
    float* rec   = xout + (size_t)N * 128;  // N*512 (final x_rec; scratch until then)
    float* recA  = rec;                     // N*256
    float* recB  = rec + (size_t)N * 256;   // N*256
    float* wsbig = (float*)d_ws;            // N*512
    float* stats = wsbig + (size_t)N * 512; // 1024 floats

    // CSR region (after stats)
    int*   row_start = (int*)(stats + 1024);  // N+1
    int*   cursor    = row_start + (N + 1);   // N
    int*   blockSums = cursor + N;            // 256
    int*   sc        = blockSums + 256;       // E
    float* sv        = (float*)(sc + E);      // E

    const size_t needed =
        ((size_t)N * 512 + 1024 + (size_t)(N + 1) + (size_t)N + 256 + 2 * (size_t)E) * 4;
    const bool use_csr = ws_size >= needed;

    const dim3 blk(256);
    const int gy = (N + 63) / 64;
    const int NB = (N + 1023) / 1024;
    const int egrid = (E + 255) / 256;
    const int rowgrid = (N + 3) / 4;

    if (use_csr) {
        // ---- build CSR (row-sorted edge list) ----
        zero_ints<<<dim3((N + 255) / 256), blk, 0, stream>>>(cursor, N);
        hist_rows<<<dim3(egrid), blk, 0, stream>>>(rows, cursor, E);
        scan_reduce<<<dim3(NB), blk, 0, stream>>>(cursor, blockSums, N);
        scan_blocksums<<<dim3(1), blk, 0, stream>>>(blockSums, NB, row_start, N, E);
        scan_final<<<dim3(NB), blk, 0, stream>>>(cursor, blockSums, row_start, cursor, N);
        scatter_edges<<<dim3(egrid), blk, 0, stream>>>(rows, cols, vals, cursor, sc, sv, E);
    }

    // 1. t0 = x @ w0 -> recA
    gemm_tile<false><<<dim3(256 / 64, gy), blk, 0, stream>>>(x, w0, recA, N, 512, 256);

    // 2. t1 = spmm(t0) + b0 -> recB
    if (use_csr) {
        spmm_csr<4><<<dim3(rowgrid), blk, 0, stream>>>(row_start, sc, sv, recA, b0, recB, N, 256);
    } else {
        const size_t n4 = (size_t)N * 256 / 4;
        fill_bias<<<dim3((unsigned)((n4 + 255) / 256)), blk, 0, stream>>>(recB, b0, n4, 63u);
        const size_t tot = (size_t)E * 64;
        spmm_edges<<<dim3((unsigned)((tot + 255) / 256)), blk, 0, stream>>>(
            rows, cols, vals, recA, recB, E, 256, 6);
    }

    // 3. t2 = bn(relu(t1)) -> recA
    zero_stats<<<dim3(1), dim3(512), 0, stream>>>(stats);
    bn_stats<<<dim3(512), blk, 0, stream>>>(recB, stats, N);
    bn_finalize<<<dim3(1), blk, 0, stream>>>(stats, 1.0f / (float)N);
    {
        const size_t n4 = (size_t)N * 256 / 4;
        bn_apply<<<dim3((unsigned)((n4 + 255) / 256)), blk, 0, stream>>>(recB, stats, recA, n4);
    }

    // 4. t3 = t2 @ w1 -> wsbig (N*128)
    gemm_tile<false><<<dim3(128 / 64, gy), blk, 0, stream>>>(recA, w1, wsbig, N, 256, 128);

    // 5. x_out = spmm(t3) + b1 -> xout
    if (use_csr) {
        spmm_csr<2><<<dim3(rowgrid), blk, 0, stream>>>(row_start, sc, sv, wsbig, b1, xout, N, 128);
    } else {
        const size_t n4 = (size_t)N * 128 / 4;
        fill_bias<<<dim3((unsigned)((n4 + 255) / 256)), blk, 0, stream>>>(xout, b1, n4, 31u);
        const size_t tot = (size_t)E * 32;
        spmm_edges<<<dim3((unsigned)((tot + 255) / 256)), blk, 0, stream>>>(
            rows, cols, vals, wsbig, xout, E, 128, 5);
    }

    // 6. r1 = relu(x_out) @ dw0 -> recB
    gemm_tile<true><<<dim3(256 / 64, gy), blk, 0, stream>>>(xout, dw0, recB, N, 128, 256);

    // 7. r2 = spmm(r1) + db0 -> recA
    if (use_csr) {
        spmm_csr<4><<<dim3(rowgrid), blk, 0, stream>>>(row_start, sc, sv, recB, db0, recA, N, 256);
    } else {
        const size_t n4 = (size_t)N * 256 / 4;
        fill_bias<<<dim3((unsigned)((n4 + 255) / 256)), blk, 0, stream>>>(recA, db0, n4, 63u);
        const size_t tot = (size_t)E * 64;
        spmm_edges<<<dim3((unsigned)((tot + 255) / 256)), blk, 0, stream>>>(
            rows, cols, vals, recB, recA, E, 256, 6);
    }

    // 8. r3 = bn(relu(r2)) -> recB
    zero_stats<<<dim3(1), dim3(512), 0, stream>>>(stats);
    bn_stats<<<dim3(512), blk, 0, stream>>>(recA, stats, N);
    bn_finalize<<<dim3(1), blk, 0, stream>>>(stats, 1.0f / (float)N);
    {
        const size_t n4 = (size_t)N * 256 / 4;
        bn_apply<<<dim3((unsigned)((n4 + 255) / 256)), blk, 0, stream>>>(recA, stats, recB, n4);
    }

    // 9. r4 = r3 @ dw1 -> wsbig (N*512)
    gemm_tile<false><<<dim3(512 / 64, gy), blk, 0, stream>>>(recB, dw1, wsbig, N, 256, 512);

    // 10. x_rec = spmm(r4) + db1 -> rec
    if (use_csr) {
        spmm_csr<8><<<dim3(rowgrid), blk, 0, stream>>>(row_start, sc, sv, wsbig, db1, rec, N, 512);
    } else {
        const size_t n4 = (size_t)N * 512 / 4;
        fill_bias<<<dim3((unsigned)((n4 + 255) / 256)), blk, 0, stream>>>(rec, db1, n4, 127u);
        const size_t tot = (size_t)E * 128;
        spmm_edges<<<dim3((unsigned)((tot + 255) / 256)), blk, 0, stream>>>(
            rows, cols, vals, wsbig, rec, E, 512, 7);
    }
}